// Round 4
// baseline (98.173 us; speedup 1.0000x reference)
//
#include <hip/hip_runtime.h>
#include <hip/hip_bf16.h>

#define NQ     8
#define SEQL   128
#define BATCHN 256
#define EMBED  512
#define DIN    520          // EMBED + NQ
#define NROWS  (SEQL*BATCHN) // 32768
#define GSTR   32           // 4 gates * 8 qubits

// ---------------------------------------------------------------------------
// DPP helpers (VALU cross-lane within 16-lane rows)
//   row_shr:N -> lane i receives lane i-N ; row_shl:N -> lane i receives i+N
// ---------------------------------------------------------------------------
#define DPP_QP(a,b,c,d) ((a)|((b)<<2)|((c)<<4)|((d)<<6))
#define DPP_SHL(n) (0x100+(n))
#define DPP_SHR(n) (0x110+(n))

template<int CTRL>
__device__ __forceinline__ float updpf(float old_, float src) {
    return __int_as_float(__builtin_amdgcn_update_dpp(
        __float_as_int(old_), __float_as_int(src), CTRL, 0xF, 0xF, false));
}

__device__ __forceinline__ float frcp(float x) { return __builtin_amdgcn_rcpf(x); }

// Pade(5,4) tanh — |z| <= 1 : err < 2e-7
__device__ __forceinline__ float tanh54(float z) {
    float w = z * z;
    float nu = fmaf(fmaf(1.0f, w, 105.f), w, 945.f) * z;
    float de = fmaf(fmaf(15.f, w, 420.f), w, 945.f);
    return nu * frcp(de);
}
// Pade(7,6) tanh — |z| <= 2.2 : err < 5e-5
__device__ __forceinline__ float tanh76(float z) {
    float w = z * z;
    float nu = fmaf(fmaf(fmaf(1.f, w, 378.f), w, 17325.f), w, 135135.f) * z;
    float de = fmaf(fmaf(fmaf(28.f, w, 3150.f), w, 62370.f), w, 135135.f);
    return nu * frcp(de);
}
// sigmoid via 0.5 + 0.5*tanh54(x/2) — |x| <= 1 safe
__device__ __forceinline__ float sigm(float x) {
    return fmaf(0.5f, tanh54(0.5f * x), 0.5f);
}

// ---------------------------------------------------------------------------
// Kernel 1: G[row*32 + c] = dot(emb[sent[row]], W_c[0:512]) + b_c   (unchanged)
// ---------------------------------------------------------------------------
__global__ __launch_bounds__(256, 2)
void k1_gates(const int* __restrict__ sent, const float* __restrict__ emb,
              const float* __restrict__ Wf, const float* __restrict__ Wi,
              const float* __restrict__ Wu, const float* __restrict__ Wo,
              const float* __restrict__ bf, const float* __restrict__ bi,
              const float* __restrict__ bu, const float* __restrict__ bo,
              float* __restrict__ G)
{
    __shared__ float Xs[128][68];
    __shared__ float Ws[64][36];
    __shared__ int   tok[128];

    const int tid  = threadIdx.x;
    const int row0 = blockIdx.x * 128;
    if (tid < 128) tok[tid] = sent[row0 + tid];

    const int rg = tid >> 3;
    const int cg = tid & 7;

    float acc[4][4] = {};
    __syncthreads();

    for (int k0 = 0; k0 < EMBED; k0 += 64) {
        #pragma unroll
        for (int i = 0; i < 8; ++i) {
            int f4 = tid + i * 256;
            int r  = f4 >> 4, k4 = f4 & 15;
            float4 v = *reinterpret_cast<const float4*>(
                &emb[(size_t)tok[r] * EMBED + k0 + k4 * 4]);
            *reinterpret_cast<float4*>(&Xs[r][k4 * 4]) = v;
        }
        #pragma unroll
        for (int i = 0; i < 8; ++i) {
            int idx = tid + i * 256;
            int c   = idx >> 6, kk = idx & 63;
            int g = c >> 3, j = c & 7;
            const float* W = (g == 0) ? Wf : (g == 1) ? Wi : (g == 2) ? Wu : Wo;
            Ws[kk][c] = W[j * DIN + k0 + kk];
        }
        __syncthreads();
        #pragma unroll
        for (int kk4 = 0; kk4 < 16; ++kk4) {
            float4 x0 = *reinterpret_cast<const float4*>(&Xs[rg +  0][kk4*4]);
            float4 x1 = *reinterpret_cast<const float4*>(&Xs[rg + 32][kk4*4]);
            float4 x2 = *reinterpret_cast<const float4*>(&Xs[rg + 64][kk4*4]);
            float4 x3 = *reinterpret_cast<const float4*>(&Xs[rg + 96][kk4*4]);
            #pragma unroll
            for (int q = 0; q < 4; ++q) {
                float4 w = *reinterpret_cast<const float4*>(&Ws[kk4*4+q][cg*4]);
                float e0 = (q==0)?x0.x:(q==1)?x0.y:(q==2)?x0.z:x0.w;
                float e1 = (q==0)?x1.x:(q==1)?x1.y:(q==2)?x1.z:x1.w;
                float e2 = (q==0)?x2.x:(q==1)?x2.y:(q==2)?x2.z:x2.w;
                float e3 = (q==0)?x3.x:(q==1)?x3.y:(q==2)?x3.z:x3.w;
                acc[0][0]+=e0*w.x; acc[0][1]+=e0*w.y; acc[0][2]+=e0*w.z; acc[0][3]+=e0*w.w;
                acc[1][0]+=e1*w.x; acc[1][1]+=e1*w.y; acc[1][2]+=e1*w.z; acc[1][3]+=e1*w.w;
                acc[2][0]+=e2*w.x; acc[2][1]+=e2*w.y; acc[2][2]+=e2*w.z; acc[2][3]+=e2*w.w;
                acc[3][0]+=e3*w.x; acc[3][1]+=e3*w.y; acc[3][2]+=e3*w.z; acc[3][3]+=e3*w.w;
            }
        }
        __syncthreads();
    }

    const int   gq = cg >> 1;
    const float* B = (gq == 0) ? bf : (gq == 1) ? bi : (gq == 2) ? bu : bo;
    float b0 = B[(cg&1)*4+0], b1 = B[(cg&1)*4+1], b2 = B[(cg&1)*4+2], b3 = B[(cg&1)*4+3];

    #pragma unroll
    for (int r = 0; r < 4; ++r) {
        float4 o = make_float4(acc[r][0]+b0, acc[r][1]+b1, acc[r][2]+b2, acc[r][3]+b3);
        size_t base = (size_t)(row0 + rg + 32*r) * GSTR + cg*4;
        *reinterpret_cast<float4*>(&G[base]) = o;
    }
}

// ---------------------------------------------------------------------------
// Kernel 2: sequential LSTM recurrence, closed-form qlayer, all-DPP comm.
//   Block = 1 wave = 4 batch rows x 16 lanes (lane m = l16&7 = qubit, mirror).
//   This block's entire G timeline (128 steps x 4 rows x 32 f32 = 64 KB) is
//   bulk-staged into LDS first -> zero HBM in the recurrence loop.
//   Activations are rational (Pade + v_rcp) -> no slow f32 divides, no exp.
// ---------------------------------------------------------------------------
__global__ __launch_bounds__(64)
void k2_lstm(const float* __restrict__ G,
             const float* __restrict__ Wf, const float* __restrict__ Wi,
             const float* __restrict__ Wu, const float* __restrict__ Wo,
             const float* __restrict__ thf, const float* __restrict__ thi,
             const float* __restrict__ thu, const float* __restrict__ tho,
             float* __restrict__ out)
{
    __shared__ float gs[SEQL * 128];      // 64 KB: [t][r*32 + g*8 + m]

    const int tid = threadIdx.x;          // 0..63 (1 wave per block)
    const int l16 = tid & 15;
    const int m   = l16 & 7;              // qubit
    const int r   = tid >> 4;             // row-in-block 0..3
    const int b   = blockIdx.x * 4 + r;

    // ---- bulk stage G -> LDS (coalesced float4; each lane 64 iters) ----
    const float* gsrc = G + (size_t)blockIdx.x * 4 * GSTR;
    #pragma unroll 4
    for (int i = 0; i < 64; ++i) {
        int sl = i * 64 + tid;            // 0..4095
        int st = sl >> 5, pc = sl & 31;   // step, 16B-piece
        float4 v = *reinterpret_cast<const float4*>(
            gsrc + (size_t)st * (BATCHN * GSTR) + pc * 4);
        *reinterpret_cast<float4*>(&gs[sl * 4]) = v;   // sl*4 == st*128 + pc*4
    }
    __syncthreads();

    const float* Wg[4] = {Wf, Wi, Wu, Wo};
    const float* tg[4] = {thf, thi, thu, tho};

    // permuted h-weights: y_g = a_g + sum_r H[r]*Whp[g][r], H[r] = h[m^r]
    float Whp[4][8], th[4];
    #pragma unroll
    for (int g = 0; g < 4; ++g) {
        th[g] = tg[g][m];
        #pragma unroll
        for (int rr = 0; rr < 8; ++rr)
            Whp[g][rr] = Wg[g][m * DIN + EMBED + (m ^ rr)];
    }

    float H[8];
    #pragma unroll
    for (int rr = 0; rr < 8; ++rr) H[rr] = 0.f;
    float c_own = 0.f, h_own = 0.f;

    const float* gp = &gs[r * 32 + m];
    float n0 = gp[0], n1 = gp[8], n2 = gp[16], n3 = gp[24];

    const bool m1 = (m >= 1), m2 = (m >= 2), m4 = (m >= 4), mz = (m == 0);

    for (int t = 0; t < SEQL; ++t) {
        // prefetch next step from LDS (off the dependence chain)
        int off = ((t + 1 < SEQL) ? t + 1 : t) * 128;
        float p0 = gp[off], p1 = gp[off + 8], p2 = gp[off + 16], p3 = gp[off + 24];

        float av[4] = {n0 + th[0], n1 + th[1], n2 + th[2], n3 + th[3]};

        float qv[4];
        #pragma unroll
        for (int g = 0; g < 4; ++g) {
            // split dot: two 4-chains + combine (depth ~5 instead of 8)
            float sA = fmaf(H[0], Whp[g][0], fmaf(H[1], Whp[g][1],
                        fmaf(H[2], Whp[g][2], H[3] * Whp[g][3])));
            float sB = fmaf(H[4], Whp[g][4], fmaf(H[5], Whp[g][5],
                        fmaf(H[6], Whp[g][6], H[7] * Whp[g][7])));
            float cs = __cosf(av[g] + sA + sB);

            // inclusive prefix product over the 8-lane group (row_shr, guarded)
            float p = cs, s;
            s = updpf<DPP_SHR(1)>(1.0f, p); p *= (m1 ? s : 1.0f);
            s = updpf<DPP_SHR(2)>(1.0f, p); p *= (m2 ? s : 1.0f);
            s = updpf<DPP_SHR(4)>(1.0f, p); p *= (m4 ? s : 1.0f);
            // full product excluding lane 0's cs (butterfly)
            float v = mz ? 1.0f : cs;
            v *= updpf<DPP_QP(1,0,3,2)>(v, v);
            v *= updpf<DPP_QP(2,3,0,1)>(v, v);
            float xl = updpf<DPP_SHL(4)>(v, v);   // lane i <- i+4 (m<4)
            float xr = updpf<DPP_SHR(4)>(v, v);   // lane i <- i-4 (m>=4)
            v *= (m4 ? xr : xl);
            qv[g] = mz ? v : p;
        }

        // activations: f,i,o sigmoid (Pade54); u tanh (Pade76). |qv|<=1.
        float fv = sigm(qv[0]);
        float iv = sigm(qv[1]);
        float uv = tanh76(qv[2]);
        float ov = sigm(qv[3]);

        c_own = fmaf(fv, c_own, iv * uv);     // |c| <= 2.07
        h_own = ov * tanh76(c_own);

        // all-gather h across the 8-lane group: H[r] = h[m^r]
        H[0] = h_own;
        H[1] = updpf<DPP_QP(1,0,3,2)>(H[0], H[0]);
        H[2] = updpf<DPP_QP(2,3,0,1)>(H[0], H[0]);
        H[3] = updpf<DPP_QP(2,3,0,1)>(H[1], H[1]);
        #pragma unroll
        for (int rr = 0; rr < 4; ++rr) {
            float xl = updpf<DPP_SHL(4)>(H[rr], H[rr]);
            float xr = updpf<DPP_SHR(4)>(H[rr], H[rr]);
            H[4 + rr] = m4 ? xr : xl;
        }

        n0 = p0; n1 = p1; n2 = p2; n3 = p3;
    }

    if (l16 < 8) out[b * NQ + m] = h_own;
}

// ---------------------------------------------------------------------------
extern "C" void kernel_launch(void* const* d_in, const int* in_sizes, int n_in,
                              void* d_out, int out_size, void* d_ws, size_t ws_size,
                              hipStream_t stream)
{
    const int*   sent = (const int*)  d_in[0];
    // d_in[1] = features : unused by the reference
    const float* emb  = (const float*)d_in[2];
    const float* Wf   = (const float*)d_in[3];
    const float* bf   = (const float*)d_in[4];
    const float* Wi   = (const float*)d_in[5];
    const float* bi   = (const float*)d_in[6];
    const float* Wu   = (const float*)d_in[7];
    const float* bu   = (const float*)d_in[8];
    const float* Wo   = (const float*)d_in[9];
    const float* bo   = (const float*)d_in[10];
    const float* thf  = (const float*)d_in[11];
    const float* thi  = (const float*)d_in[12];
    const float* thu  = (const float*)d_in[13];
    const float* tho  = (const float*)d_in[14];
    float* out = (float*)d_out;

    float* G = (float*)d_ws;   // 32768 * 32 * 4B = 4 MB

    k1_gates<<<NROWS/128, 256, 0, stream>>>(sent, emb, Wf, Wi, Wu, Wo,
                                            bf, bi, bu, bo, G);
    k2_lstm<<<BATCHN/4, 64, 0, stream>>>(G, Wf, Wi, Wu, Wo,
                                         thf, thi, thu, tho, out);
}

// Round 5
// 59.428 us; speedup vs baseline: 1.6520x; 1.6520x over previous
//
#include <hip/hip_runtime.h>
#include <hip/hip_bf16.h>

#define NQ     8
#define SEQL   128
#define BATCHN 256
#define EMBED  512
#define DIN    520          // EMBED + NQ
#define NROWS  (SEQL*BATCHN) // 32768
#define GSTR   32           // 4 gates * 8 qubits
#define INV2PI 0.15915494309189535f

// ---------------------------------------------------------------------------
// DPP helpers: row_shr:N -> lane i gets lane i-N ; row_shl:N -> lane i+N
// ---------------------------------------------------------------------------
#define DPP_QP(a,b,c,d) ((a)|((b)<<2)|((c)<<4)|((d)<<6))
#define DPP_SHL(n) (0x100+(n))
#define DPP_SHR(n) (0x110+(n))

template<int CTRL>
__device__ __forceinline__ float updpf(float old_, float src) {
    return __int_as_float(__builtin_amdgcn_update_dpp(
        __float_as_int(old_), __float_as_int(src), CTRL, 0xF, 0xF, false));
}
// ds_swizzle BitMode: dst lane i reads ((i & and) | or) ^ xor  (per 32 lanes)
template<int OFF>
__device__ __forceinline__ float swzf(float x) {
    return __int_as_float(__builtin_amdgcn_ds_swizzle(__float_as_int(x), OFF));
}

__device__ __forceinline__ float frcp(float x) { return __builtin_amdgcn_rcpf(x); }

// Pade(5,4) tanh — |z| <= 1 : err < 2e-7
__device__ __forceinline__ float tanh54(float z) {
    float w = z * z;
    float nu = fmaf(fmaf(1.0f, w, 105.f), w, 945.f) * z;
    float de = fmaf(fmaf(15.f, w, 420.f), w, 945.f);
    return nu * frcp(de);
}
// Pade(7,6) tanh — |z| <= 2.2 : err < 5e-5
__device__ __forceinline__ float tanh76(float z) {
    float w = z * z;
    float nu = fmaf(fmaf(fmaf(1.f, w, 378.f), w, 17325.f), w, 135135.f) * z;
    float de = fmaf(fmaf(fmaf(28.f, w, 3150.f), w, 62370.f), w, 135135.f);
    return nu * frcp(de);
}

// ---------------------------------------------------------------------------
// Kernel 1: G[row*32+c] = (emb[sent[row]].W_c + b_c + th_c) * INV2PI
//   64-row x 32-col tile, 8 outputs/thread (rows rg*2, rg*2+1 x 4 cols).
// ---------------------------------------------------------------------------
__global__ __launch_bounds__(256, 2)
void k1_gates(const int* __restrict__ sent, const float* __restrict__ emb,
              const float* __restrict__ Wf, const float* __restrict__ Wi,
              const float* __restrict__ Wu, const float* __restrict__ Wo,
              const float* __restrict__ bf, const float* __restrict__ bi,
              const float* __restrict__ bu, const float* __restrict__ bo,
              const float* __restrict__ thf, const float* __restrict__ thi,
              const float* __restrict__ thu, const float* __restrict__ tho,
              float* __restrict__ G)
{
    __shared__ float Xs[64][68];
    __shared__ float Ws[64][36];
    __shared__ int   tok[64];

    const int tid  = threadIdx.x;
    const int row0 = blockIdx.x * 64;
    if (tid < 64) tok[tid] = sent[row0 + tid];

    const int rg = tid >> 3;
    const int cg = tid & 7;

    float acc0[4] = {0.f,0.f,0.f,0.f};
    float acc1[4] = {0.f,0.f,0.f,0.f};
    __syncthreads();

    for (int k0 = 0; k0 < EMBED; k0 += 64) {
        #pragma unroll
        for (int i = 0; i < 4; ++i) {
            int f4 = tid + i * 256;
            int r  = f4 >> 4, k4 = f4 & 15;
            float4 v = *reinterpret_cast<const float4*>(
                &emb[(size_t)tok[r] * EMBED + k0 + k4 * 4]);
            *reinterpret_cast<float4*>(&Xs[r][k4 * 4]) = v;
        }
        #pragma unroll
        for (int i = 0; i < 8; ++i) {
            int idx = tid + i * 256;
            int c   = idx >> 6, kk = idx & 63;
            int g = c >> 3, j = c & 7;
            const float* W = (g == 0) ? Wf : (g == 1) ? Wi : (g == 2) ? Wu : Wo;
            Ws[kk][c] = W[j * DIN + k0 + kk];
        }
        __syncthreads();
        #pragma unroll
        for (int kk4 = 0; kk4 < 16; ++kk4) {
            float4 x0 = *reinterpret_cast<const float4*>(&Xs[rg*2+0][kk4*4]);
            float4 x1 = *reinterpret_cast<const float4*>(&Xs[rg*2+1][kk4*4]);
            #pragma unroll
            for (int q = 0; q < 4; ++q) {
                float4 w = *reinterpret_cast<const float4*>(&Ws[kk4*4+q][cg*4]);
                float xa = (q==0)?x0.x:(q==1)?x0.y:(q==2)?x0.z:x0.w;
                float xb = (q==0)?x1.x:(q==1)?x1.y:(q==2)?x1.z:x1.w;
                acc0[0] += xa*w.x; acc0[1] += xa*w.y; acc0[2] += xa*w.z; acc0[3] += xa*w.w;
                acc1[0] += xb*w.x; acc1[1] += xb*w.y; acc1[2] += xb*w.z; acc1[3] += xb*w.w;
            }
        }
        __syncthreads();
    }

    // combined bias: (b + theta) * INV2PI ; output scaled to revolutions
    const int   gq = cg >> 1;
    const float* B  = (gq == 0) ? bf  : (gq == 1) ? bi  : (gq == 2) ? bu  : bo;
    const float* Th = (gq == 0) ? thf : (gq == 1) ? thi : (gq == 2) ? thu : tho;
    float bc[4];
    #pragma unroll
    for (int n = 0; n < 4; ++n)
        bc[n] = (B[(cg&1)*4+n] + Th[(cg&1)*4+n]) * INV2PI;

    float4 o0 = make_float4(fmaf(acc0[0],INV2PI,bc[0]), fmaf(acc0[1],INV2PI,bc[1]),
                            fmaf(acc0[2],INV2PI,bc[2]), fmaf(acc0[3],INV2PI,bc[3]));
    float4 o1 = make_float4(fmaf(acc1[0],INV2PI,bc[0]), fmaf(acc1[1],INV2PI,bc[1]),
                            fmaf(acc1[2],INV2PI,bc[2]), fmaf(acc1[3],INV2PI,bc[3]));
    size_t base = (size_t)(row0 + rg*2) * GSTR + cg*4;
    *reinterpret_cast<float4*>(&G[base])        = o0;
    *reinterpret_cast<float4*>(&G[base + GSTR]) = o1;
}

// ---------------------------------------------------------------------------
// Kernel 2: LSTM recurrence, closed-form qlayer. 32 lanes/row, 2 rows/wave.
//   lane32 = g*8+j : each lane owns ONE gate of ONE qubit (no redundancy).
//   G pre-scaled to revolutions, theta+bias folded in -> cs = v_cos(y+h.W).
//   qubit-group scan/butterfly: DPP. gate gather: 4 parallel ds_swizzle
//   (and=7,or=g'*8): lane <- lane&7 | g'<<3.
// ---------------------------------------------------------------------------
__global__ __launch_bounds__(64)
void k2_lstm(const float* __restrict__ G,
             const float* __restrict__ Wf, const float* __restrict__ Wi,
             const float* __restrict__ Wu, const float* __restrict__ Wo,
             float* __restrict__ out)
{
    __shared__ float gs[SEQL * 64];       // 32 KB: [t][r*32 + g*8 + j]

    const int tid = threadIdx.x;          // 0..63, 1 wave
    const int l32 = tid & 31;
    const int g   = l32 >> 3;             // gate 0..3 (f,i,u,o)
    const int j   = l32 & 7;              // qubit
    const int r   = tid >> 5;             // row-in-block
    const int b   = blockIdx.x * 2 + r;

    // ---- bulk stage this block's G timeline (128 t x 2 rows x 32 f32) ----
    {
        const float* gsrc = G + (size_t)blockIdx.x * 64;
        #pragma unroll 4
        for (int i = 0; i < 32; ++i) {
            int sl = i * 64 + tid;        // float4 slot 0..2047
            int st = sl >> 4, pc = sl & 15;
            float4 v = *reinterpret_cast<const float4*>(
                gsrc + (size_t)st * (BATCHN * GSTR) + pc * 4);
            *reinterpret_cast<float4*>(&gs[sl * 4]) = v;
        }
    }
    __syncthreads();

    const float* Wsel = (g==0) ? Wf : (g==1) ? Wi : (g==2) ? Wu : Wo;

    // permuted, pre-scaled h-weights: dot = sum_r H[r]*Whp[r], H[r]=h[j^r]
    float Whp[8];
    #pragma unroll
    for (int rr = 0; rr < 8; ++rr)
        Whp[rr] = Wsel[j * DIN + EMBED + (j ^ rr)] * INV2PI;

    float H[8];
    #pragma unroll
    for (int rr = 0; rr < 8; ++rr) H[rr] = 0.f;
    float c_own = 0.f, h_own = 0.f;

    const float* gp = gs + tid;           // t*64 + r*32 + l32 == t*64 + tid
    float n = gp[0];

    const bool m1 = (j >= 1), m2 = (j >= 2), m4 = (j >= 4), jz = (j == 0);
    const bool isU = (g == 2);

    for (int t = 0; t < SEQL; ++t) {
        // prefetch next step's value from LDS (off the dependence chain)
        float nn = gp[((t + 1 < SEQL) ? t + 1 : t) * 64];

        // a (revolutions) = G + h-dot (split 2x4 chains)
        float sA = fmaf(H[0], Whp[0], fmaf(H[1], Whp[1],
                    fmaf(H[2], Whp[2], H[3] * Whp[3])));
        float sB = fmaf(H[4], Whp[4], fmaf(H[5], Whp[5],
                    fmaf(H[6], Whp[6], H[7] * Whp[7])));
        float cs = __builtin_amdgcn_cosf(n + sA + sB);

        // inclusive prefix product over qubit group (row_shr, guarded)
        float p = cs, s;
        s = updpf<DPP_SHR(1)>(1.0f, p); p *= (m1 ? s : 1.0f);
        s = updpf<DPP_SHR(2)>(1.0f, p); p *= (m2 ? s : 1.0f);
        s = updpf<DPP_SHR(4)>(1.0f, p); p *= (m4 ? s : 1.0f);
        // product of cs_1..cs_7 (butterfly; lane 0 contributes 1)
        float v = jz ? 1.0f : cs;
        v *= updpf<DPP_QP(1,0,3,2)>(v, v);
        v *= updpf<DPP_QP(2,3,0,1)>(v, v);
        float xl = updpf<DPP_SHL(4)>(v, v);
        float xr = updpf<DPP_SHR(4)>(v, v);
        v *= (m4 ? xr : xl);
        float qv = jz ? v : p;

        // activation: u -> tanh(qv); f,i,o -> sigmoid(qv)=0.5+0.5*tanh(qv/2)
        float z  = isU ? qv : 0.5f * qv;
        float tt = tanh54(z);
        float act = isU ? tt : fmaf(0.5f, tt, 0.5f);

        // gather the 4 gate values for this qubit (parallel swizzles)
        float fv = swzf<0x0007>(act);     // lane & 7        -> gate f
        float iv = swzf<0x0107>(act);     // (lane&7)|8      -> gate i
        float uv = swzf<0x0207>(act);     // (lane&7)|16     -> gate u
        float ov = swzf<0x0307>(act);     // (lane&7)|24     -> gate o

        c_own = fmaf(fv, c_own, iv * uv); // |c| <= 2.07
        h_own = ov * tanh76(c_own);

        // all-gather h across the 8-lane qubit group: H[r] = h[j^r]
        H[0] = h_own;
        H[1] = updpf<DPP_QP(1,0,3,2)>(H[0], H[0]);
        H[2] = updpf<DPP_QP(2,3,0,1)>(H[0], H[0]);
        H[3] = updpf<DPP_QP(2,3,0,1)>(H[1], H[1]);
        #pragma unroll
        for (int rr = 0; rr < 4; ++rr) {
            float yl = updpf<DPP_SHL(4)>(H[rr], H[rr]);
            float yr = updpf<DPP_SHR(4)>(H[rr], H[rr]);
            H[4 + rr] = m4 ? yr : yl;
        }

        n = nn;
    }

    if (l32 < 8) out[b * NQ + j] = h_own;
}

// ---------------------------------------------------------------------------
extern "C" void kernel_launch(void* const* d_in, const int* in_sizes, int n_in,
                              void* d_out, int out_size, void* d_ws, size_t ws_size,
                              hipStream_t stream)
{
    const int*   sent = (const int*)  d_in[0];
    // d_in[1] = features : unused by the reference
    const float* emb  = (const float*)d_in[2];
    const float* Wf   = (const float*)d_in[3];
    const float* bf   = (const float*)d_in[4];
    const float* Wi   = (const float*)d_in[5];
    const float* bi   = (const float*)d_in[6];
    const float* Wu   = (const float*)d_in[7];
    const float* bu   = (const float*)d_in[8];
    const float* Wo   = (const float*)d_in[9];
    const float* bo   = (const float*)d_in[10];
    const float* thf  = (const float*)d_in[11];
    const float* thi  = (const float*)d_in[12];
    const float* thu  = (const float*)d_in[13];
    const float* tho  = (const float*)d_in[14];
    float* out = (float*)d_out;

    float* G = (float*)d_ws;   // 32768 * 32 * 4B = 4 MB

    k1_gates<<<NROWS/64, 256, 0, stream>>>(sent, emb, Wf, Wi, Wu, Wo,
                                           bf, bi, bu, bo,
                                           thf, thi, thu, tho, G);
    k2_lstm<<<BATCHN/2, 64, 0, stream>>>(G, Wf, Wi, Wu, Wo, out);
}